// Round 2
// baseline (774.061 us; speedup 1.0000x reference)
//
#include <hip/hip_runtime.h>
#include <hip/hip_bf16.h>

#define BB   16
#define CCH  256
#define DQK  32
#define NTOK 4096

typedef __attribute__((ext_vector_type(8))) short short8;
typedef __attribute__((ext_vector_type(4))) float f32x4;
typedef unsigned short u16t;
typedef unsigned int   u32t;

__device__ __forceinline__ u16t f2bf(float f){
  u32t u = __builtin_bit_cast(u32t, f);
  u += 0x7FFFu + ((u >> 16) & 1u);
  return (u16t)(u >> 16);
}

// ---------------- Kernel 0: x [B][C][N] f32 -> xT [B][N][C] bf16 ----------------
__global__ __launch_bounds__(256) void k_xpose(const float* __restrict__ x,
                                               u16t* __restrict__ xT){
  __shared__ u16t tile[64][66];
  const int b = blockIdx.z, c0 = blockIdx.y * 64, n0 = blockIdx.x * 64;
  const int t = threadIdx.x;
  const int cg = t & 15, r0 = t >> 4;
  const float* xb = x + ((size_t)b * CCH + c0) * NTOK + n0;
  #pragma unroll
  for (int p = 0; p < 4; ++p){
    const int r = r0 + p * 16;
    float4 v = *(const float4*)(xb + (size_t)r * NTOK + cg * 4);
    tile[r][cg*4+0] = f2bf(v.x);
    tile[r][cg*4+1] = f2bf(v.y);
    tile[r][cg*4+2] = f2bf(v.z);
    tile[r][cg*4+3] = f2bf(v.w);
  }
  __syncthreads();
  const int nl = t >> 2, cc = (t & 3) * 16;
  u32t u[8];
  #pragma unroll
  for (int i = 0; i < 8; ++i)
    u[i] = (u32t)tile[cc + 2*i][nl] | ((u32t)tile[cc + 2*i + 1][nl] << 16);
  u16t* o = xT + ((size_t)b * NTOK + n0 + nl) * CCH + c0 + cc;
  *(uint4*)(o)     = make_uint4(u[0], u[1], u[2], u[3]);
  *(uint4*)(o + 8) = make_uint4(u[4], u[5], u[6], u[7]);
}

// ---------------- Kernel 1: projections Q,K [B][N][32], V [B][C][N] (bf16) ------
// grid (NTOK/64, 5, BB), block 256. ot=0: waves 0,1 -> Q rows, waves 2,3 -> K rows.
// ot=1..4: V rows (ot-1)*64 + wave*16.
__global__ __launch_bounds__(256) void k_proj(const u16t* __restrict__ xT,
    const float* __restrict__ Wq, const float* __restrict__ bq,
    const float* __restrict__ Wk, const float* __restrict__ bk,
    const float* __restrict__ Wv, const float* __restrict__ bv,
    u16t* __restrict__ Q, u16t* __restrict__ K, u16t* __restrict__ V){
  const int b = blockIdx.z, ot = blockIdx.y, nb = blockIdx.x * 64;
  const int tid = threadIdx.x;
  const int w = tid >> 6, lane = tid & 63;
  const int lo = lane & 15, g = lane >> 4;
  const float* W; const float* bias; int ob; int mode;
  if (ot == 0){
    if (w < 2){ W = Wq; bias = bq; ob = w * 16;       mode = 0; }
    else      { W = Wk; bias = bk; ob = (w - 2) * 16; mode = 1; }
  } else {      W = Wv; bias = bv; ob = (ot - 1) * 64 + w * 16; mode = 2; }

  f32x4 acc[4];
  #pragma unroll
  for (int s = 0; s < 4; ++s) acc[s] = (f32x4){0.f, 0.f, 0.f, 0.f};

  const u16t* xb = xT + ((size_t)b * NTOK + nb) * CCH;
  for (int kc = 0; kc < CCH; kc += 32){
    const float* wr = W + (size_t)(ob + lo) * CCH + kc + g * 8;
    float4 a0 = *(const float4*)wr;
    float4 a1 = *(const float4*)(wr + 4);
    short8 af;
    af[0] = (short)f2bf(a0.x); af[1] = (short)f2bf(a0.y);
    af[2] = (short)f2bf(a0.z); af[3] = (short)f2bf(a0.w);
    af[4] = (short)f2bf(a1.x); af[5] = (short)f2bf(a1.y);
    af[6] = (short)f2bf(a1.z); af[7] = (short)f2bf(a1.w);
    #pragma unroll
    for (int s = 0; s < 4; ++s){
      short8 bf = *(const short8*)(xb + (size_t)(s * 16 + lo) * CCH + kc + g * 8);
      acc[s] = __builtin_amdgcn_mfma_f32_16x16x32_bf16(af, bf, acc[s], 0, 0, 0);
    }
  }
  #pragma unroll
  for (int s = 0; s < 4; ++s){
    #pragma unroll
    for (int r = 0; r < 4; ++r){
      const int o = ob + 4 * g + r;
      const int n = nb + s * 16 + lo;
      const float val = acc[s][r] + bias[o];
      const u16t h = f2bf(val);
      if (mode == 0)      Q[((size_t)b * NTOK + n) * DQK + o] = h;
      else if (mode == 1) K[((size_t)b * NTOK + n) * DQK + o] = h;
      else                V[((size_t)b * CCH + o) * NTOK + n] = h;
    }
  }
}

// ---------------- Kernel 2: flash attention + epilogue ----------------
// grid 1024 = qt*16 + b  (so XCD = bid%8 = b%8 -> per-batch L2 pinning), block 256.
// Each wave owns 16 queries (col = lane&15). Swapped QK^T: S'[j][q] = mfma(K, Q).
__global__ __launch_bounds__(256) void k_attn(
    const u16t* __restrict__ Q, const u16t* __restrict__ K, const u16t* __restrict__ V,
    const float* __restrict__ x, const float* __restrict__ gamma,
    float* __restrict__ out){
  __shared__ __align__(16) u16t Vt[CCH * 64];        // 32 KB, 16B-slot XOR swizzled
  __shared__ __align__(16) u16t Plds[4][16 * 72];    // per-wave P round-trip
  const int bid = blockIdx.x;
  const int b = bid & 15, qt = bid >> 4;
  const int qb = qt * 64;
  const int tid = threadIdx.x, w = tid >> 6, lane = tid & 63;
  const int lo = lane & 15, g = lane >> 4;

  const u16t* Qb = Q + (size_t)b * NTOK * DQK;
  const u16t* Kb = K + (size_t)b * NTOK * DQK;
  const u16t* Vb = V + (size_t)b * CCH * NTOK;

  // hoisted Q fragment (B-operand): n = this lane's query, k = d
  const short8 qf = *(const short8*)(Qb + (size_t)(qb + w * 16 + lo) * DQK + g * 8);

  float m = -INFINITY, l = 0.f;
  f32x4 acc[16];
  #pragma unroll
  for (int i = 0; i < 16; ++i) acc[i] = (f32x4){0.f, 0.f, 0.f, 0.f};

  u16t* Pw = &Plds[w][0];

  for (int kt = 0; kt < NTOK / 64; ++kt){
    const int jb = kt * 64;

    // stage V tile (global, linear/coalesced) into registers
    uint4 vst[8];
    #pragma unroll
    for (int i = 0; i < 8; ++i){
      const int a = w * 8192 + i * 1024 + lane * 16;  // byte within 32KB tile
      const int row = a >> 7;                          // channel c
      const int col8 = (a >> 4) & 7;                   // 16B slot in row
      vst[i] = *(const uint4*)(Vb + (size_t)row * NTOK + jb + col8 * 8);
    }

    // K fragments (A-operand rows = keys)
    short8 kf[4];
    #pragma unroll
    for (int s = 0; s < 4; ++s)
      kf[s] = *(const short8*)(Kb + (size_t)(jb + s * 16 + lo) * DQK + g * 8);

    // S'[j][q] = sum_d K[j][d] Q[q][d]
    f32x4 sacc[4];
    #pragma unroll
    for (int s = 0; s < 4; ++s)
      sacc[s] = __builtin_amdgcn_mfma_f32_16x16x32_bf16(kf[s], qf,
                    (f32x4){0.f, 0.f, 0.f, 0.f}, 0, 0, 0);

    // online softmax for this lane's query (col lo); rows spread over s,r and lane groups
    float mx = sacc[0][0];
    #pragma unroll
    for (int s = 0; s < 4; ++s)
      #pragma unroll
      for (int r = 0; r < 4; ++r) mx = fmaxf(mx, sacc[s][r]);
    mx = fmaxf(mx, __shfl_xor(mx, 16));
    mx = fmaxf(mx, __shfl_xor(mx, 32));
    const float mnew = fmaxf(m, mx);
    const float alpha = __expf(m - mnew);
    float p[16];
    float rs = 0.f;
    #pragma unroll
    for (int s = 0; s < 4; ++s)
      #pragma unroll
      for (int r = 0; r < 4; ++r){
        const float e = __expf(sacc[s][r] - mnew);
        p[4 * s + r] = e;
        rs += e;
      }
    rs += __shfl_xor(rs, 16);
    rs += __shfl_xor(rs, 32);
    l = l * alpha + rs;
    m = mnew;
    #pragma unroll
    for (int i = 0; i < 16; ++i) acc[i] = acc[i] * alpha;

    // pack P (bf16 pairs, consecutive j) into per-wave LDS: row = q (lo), col = local j
    #pragma unroll
    for (int s = 0; s < 4; ++s)
      #pragma unroll
      for (int h = 0; h < 2; ++h){
        const u32t pk = (u32t)f2bf(p[4 * s + 2 * h]) |
                        ((u32t)f2bf(p[4 * s + 2 * h + 1]) << 16);
        *(u32t*)(Pw + lo * 72 + 16 * s + 4 * g + 2 * h) = pk;
      }

    __syncthreads();   // all waves finished reading previous V tile
    // write V tile with XOR slot swizzle (kills 16-way conflict on column reads)
    #pragma unroll
    for (int i = 0; i < 8; ++i){
      const int a = w * 8192 + i * 1024 + lane * 16;
      const int row = a >> 7;
      const int col8 = (a >> 4) & 7;
      const int sl = col8 ^ (row & 7);
      *(uint4*)((char*)Vt + row * 128 + sl * 16) = vst[i];
    }
    __syncthreads();   // V tile visible to all waves

    // read P as MFMA-B fragments: k = local j, n = q
    short8 pb[2];
    #pragma unroll
    for (int t = 0; t < 2; ++t)
      pb[t] = *(const short8*)(Pw + lo * 72 + 32 * t + 8 * g);

    // O'[c][q] += V[c][j] P'[j][q]
    #pragma unroll
    for (int sc = 0; sc < 16; ++sc){
      const int c0 = sc * 16 + lo;
      #pragma unroll
      for (int t = 0; t < 2; ++t){
        const int sl = (4 * t + g) ^ (lo & 7);
        const short8 vf = *(const short8*)((const char*)Vt + c0 * 128 + sl * 16);
        acc[sc] = __builtin_amdgcn_mfma_f32_16x16x32_bf16(vf, pb[t], acc[sc], 0, 0, 0);
      }
    }
  }

  // epilogue: out = gamma * O/l + x   (out layout [B][C][N] == [B,C,H,W])
  const float inv = 1.0f / l;
  const float gm = gamma[0];
  const int n = qb + w * 16 + lo;
  #pragma unroll
  for (int sc = 0; sc < 16; ++sc){
    #pragma unroll
    for (int r = 0; r < 4; ++r){
      const int c = sc * 16 + 4 * g + r;
      const size_t idx = ((size_t)b * CCH + c) * NTOK + n;
      out[idx] = gm * (acc[sc][r] * inv) + x[idx];
    }
  }
}

extern "C" void kernel_launch(void* const* d_in, const int* in_sizes, int n_in,
                              void* d_out, int out_size, void* d_ws, size_t ws_size,
                              hipStream_t stream) {
  const float* x     = (const float*)d_in[0];
  const float* Wq    = (const float*)d_in[1];
  const float* bq    = (const float*)d_in[2];
  const float* Wk    = (const float*)d_in[3];
  const float* bk    = (const float*)d_in[4];
  const float* Wv    = (const float*)d_in[5];
  const float* bv    = (const float*)d_in[6];
  const float* gamma = (const float*)d_in[7];
  float* out = (float*)d_out;

  char* ws = (char*)d_ws;
  u16t* xT = (u16t*)(ws);                      // 32 MB
  u16t* Qw = (u16t*)(ws + 33554432);           //  4 MB
  u16t* Kw = (u16t*)(ws + 37748736);           //  4 MB
  u16t* Vw = (u16t*)(ws + 41943040);           // 32 MB  (total 72 MB)

  hipLaunchKernelGGL(k_xpose, dim3(NTOK / 64, CCH / 64, BB), dim3(256), 0, stream,
                     x, xT);
  hipLaunchKernelGGL(k_proj, dim3(NTOK / 64, 5, BB), dim3(256), 0, stream,
                     xT, Wq, bq, Wk, bk, Wv, bv, Qw, Kw, Vw);
  hipLaunchKernelGGL(k_attn, dim3(BB * (NTOK / 64)), dim3(256), 0, stream,
                     Qw, Kw, Vw, x, gamma, out);
}

// Round 3
// 313.408 us; speedup vs baseline: 2.4698x; 2.4698x over previous
//
#include <hip/hip_runtime.h>
#include <hip/hip_bf16.h>

#define BB   16
#define CCH  256
#define DQK  32
#define NTOK 4096

typedef __attribute__((ext_vector_type(8)))  short short8;
typedef __attribute__((ext_vector_type(4)))  float f32x4;
typedef __attribute__((ext_vector_type(16))) float f32x16;
typedef unsigned short u16t;
typedef unsigned int   u32t;

__device__ __forceinline__ u16t f2bf(float f){
  u32t u = __builtin_bit_cast(u32t, f);
  u += 0x7FFFu + ((u >> 16) & 1u);
  return (u16t)(u >> 16);
}
__device__ __forceinline__ u32t pk2(float a, float b){
  return (u32t)f2bf(a) | ((u32t)f2bf(b) << 16);
}
__device__ __forceinline__ void gload16(const void* g, void* l){
  __builtin_amdgcn_global_load_lds(
      (const __attribute__((address_space(1))) void*)g,
      (__attribute__((address_space(3))) void*)l, 16, 0, 0);
}
__device__ __forceinline__ f32x16 zero16(){
  f32x16 z;
  #pragma unroll
  for (int i = 0; i < 16; ++i) z[i] = 0.f;
  return z;
}

// ---------------- Kernel 0: x [B][C][N] f32 -> xT [B][N][C] bf16 ----------------
__global__ __launch_bounds__(256) void k_xpose(const float* __restrict__ x,
                                               u16t* __restrict__ xT){
  __shared__ u16t tile[64][66];
  const int b = blockIdx.z, c0 = blockIdx.y * 64, n0 = blockIdx.x * 64;
  const int t = threadIdx.x;
  const int cg = t & 15, r0 = t >> 4;
  const float* xb = x + ((size_t)b * CCH + c0) * NTOK + n0;
  #pragma unroll
  for (int p = 0; p < 4; ++p){
    const int r = r0 + p * 16;
    float4 v = *(const float4*)(xb + (size_t)r * NTOK + cg * 4);
    tile[r][cg*4+0] = f2bf(v.x);
    tile[r][cg*4+1] = f2bf(v.y);
    tile[r][cg*4+2] = f2bf(v.z);
    tile[r][cg*4+3] = f2bf(v.w);
  }
  __syncthreads();
  const int nl = t >> 2, cc = (t & 3) * 16;
  u32t u[8];
  #pragma unroll
  for (int i = 0; i < 8; ++i)
    u[i] = (u32t)tile[cc + 2*i][nl] | ((u32t)tile[cc + 2*i + 1][nl] << 16);
  u16t* o = xT + ((size_t)b * NTOK + n0 + nl) * CCH + c0 + cc;
  *(uint4*)(o)     = make_uint4(u[0], u[1], u[2], u[3]);
  *(uint4*)(o + 8) = make_uint4(u[4], u[5], u[6], u[7]);
}

// ---------------- Kernel 1: projections Q,K [B][N][32], V [B][C][N] (bf16) ------
__global__ __launch_bounds__(256) void k_proj(const u16t* __restrict__ xT,
    const float* __restrict__ Wq, const float* __restrict__ bq,
    const float* __restrict__ Wk, const float* __restrict__ bk,
    const float* __restrict__ Wv, const float* __restrict__ bv,
    u16t* __restrict__ Q, u16t* __restrict__ K, u16t* __restrict__ V){
  const int b = blockIdx.z, ot = blockIdx.y, nb = blockIdx.x * 64;
  const int tid = threadIdx.x;
  const int w = tid >> 6, lane = tid & 63;
  const int lo = lane & 15, g = lane >> 4;
  const float* W; const float* bias; int ob; int mode;
  if (ot == 0){
    if (w < 2){ W = Wq; bias = bq; ob = w * 16;       mode = 0; }
    else      { W = Wk; bias = bk; ob = (w - 2) * 16; mode = 1; }
  } else {      W = Wv; bias = bv; ob = (ot - 1) * 64 + w * 16; mode = 2; }

  f32x4 acc[4];
  #pragma unroll
  for (int s = 0; s < 4; ++s) acc[s] = (f32x4){0.f, 0.f, 0.f, 0.f};

  const u16t* xb = xT + ((size_t)b * NTOK + nb) * CCH;
  for (int kc = 0; kc < CCH; kc += 32){
    const float* wr = W + (size_t)(ob + lo) * CCH + kc + g * 8;
    float4 a0 = *(const float4*)wr;
    float4 a1 = *(const float4*)(wr + 4);
    short8 af;
    af[0] = (short)f2bf(a0.x); af[1] = (short)f2bf(a0.y);
    af[2] = (short)f2bf(a0.z); af[3] = (short)f2bf(a0.w);
    af[4] = (short)f2bf(a1.x); af[5] = (short)f2bf(a1.y);
    af[6] = (short)f2bf(a1.z); af[7] = (short)f2bf(a1.w);
    #pragma unroll
    for (int s = 0; s < 4; ++s){
      short8 bf = *(const short8*)(xb + (size_t)(s * 16 + lo) * CCH + kc + g * 8);
      acc[s] = __builtin_amdgcn_mfma_f32_16x16x32_bf16(af, bf, acc[s], 0, 0, 0);
    }
  }
  #pragma unroll
  for (int s = 0; s < 4; ++s){
    #pragma unroll
    for (int r = 0; r < 4; ++r){
      const int o = ob + 4 * g + r;
      const int n = nb + s * 16 + lo;
      const float val = acc[s][r] + bias[o];
      const u16t h = f2bf(val);
      if (mode == 0)      Q[((size_t)b * NTOK + n) * DQK + o] = h;
      else if (mode == 1) K[((size_t)b * NTOK + n) * DQK + o] = h;
      else                V[((size_t)b * CCH + o) * NTOK + n] = h;
    }
  }
}

// ---------------- Kernel 2: flash attention + epilogue ----------------
// grid 512, block 256 (4 waves). Wave owns 32 queries via 32x32x16 MFMA.
// b = ((bid&7)<<1)|((bid>>3)&1): XCD (bid%8) pinned to 2 batches for L2 locality.
// V tile [256 c][64 j] bf16, XOR-swizzled 16B slots, double-buffered via
// global_load_lds with pre-swizzled global source (LDS stays linear).
// P redistribution in-register: bf16 pack + shfl_xor(32). Defer-max (THR=8).
__global__ __launch_bounds__(256, 2) void k_attn(
    const u16t* __restrict__ Q, const u16t* __restrict__ K, const u16t* __restrict__ V,
    const float* __restrict__ x, const float* __restrict__ gamma,
    float* __restrict__ out){
  __shared__ __align__(16) u16t Vt[2][CCH * 64];   // 2 x 32 KB
  __shared__ __align__(16) u16t Kt[2][64 * DQK];   // 2 x 4 KB
  const int bid = blockIdx.x;
  const int b  = ((bid & 7) << 1) | ((bid >> 3) & 1);
  const int qt = bid >> 4;                  // 0..31
  const int tid = threadIdx.x, w = tid >> 6, lane = tid & 63;
  const int ql = lane & 31, hi = lane >> 5;
  const int qg = qt * 128 + w * 32;         // wave's query base

  const u16t* Qb = Q + (size_t)b * NTOK * DQK;
  const u16t* Kb = K + (size_t)b * NTOK * DQK;
  const u16t* Vb = V + (size_t)b * CCH * NTOK;

  // Q fragments (B-operand, hoisted): k = d, n = q
  const short8 qf0 = *(const short8*)(Qb + (size_t)(qg + ql) * DQK + hi * 8);
  const short8 qf1 = *(const short8*)(Qb + (size_t)(qg + ql) * DQK + 16 + hi * 8);

  f32x16 acc[8];
  #pragma unroll
  for (int c = 0; c < 8; ++c) acc[c] = zero16();
  float m = -INFINITY, l = 0.f;

  // V staging: lane constants. LDS off (in tile) = w*8192 + i*1024 + lane*16 bytes
  //   -> row = w*64 + i*8 + (lane>>3), slot = lane&7; global j-span = slot ^ (row&7)
  const int vrow0 = w * 64 + (lane >> 3);
  const int jsrc  = ((lane & 7) ^ (lane >> 3)) * 8;
  // K staging: row = w*16 + (lane>>2), d-span = (lane&3)*8 (linear, no swizzle)
  const int krow = w * 16 + (lane >> 2);
  const int kcol = (lane & 3) * 8;

  // prologue: stage tile 0
  #pragma unroll
  for (int i = 0; i < 8; ++i)
    gload16(Vb + (size_t)(vrow0 + i * 8) * NTOK + jsrc,
            &Vt[0][w * 4096 + i * 512]);
  gload16(Kb + (size_t)krow * DQK + kcol, &Kt[0][w * 512]);
  __syncthreads();

  for (int t = 0; t < 64; ++t){
    const int cur = t & 1;
    if (t < 63){
      const int jb2 = (t + 1) * 64;
      #pragma unroll
      for (int i = 0; i < 8; ++i)
        gload16(Vb + (size_t)(vrow0 + i * 8) * NTOK + jb2 + jsrc,
                &Vt[cur ^ 1][w * 4096 + i * 512]);
      gload16(Kb + (size_t)(jb2 + krow) * DQK + kcol, &Kt[cur ^ 1][w * 512]);
    }

    // ---- QK^T: S'[j][q] = mfma(K, Q), two 32-j subtiles ----
    const u16t* kb = &Kt[cur][0];
    const short8 kf00 = *(const short8*)(kb + (size_t)ql * DQK + hi * 8);
    const short8 kf01 = *(const short8*)(kb + (size_t)ql * DQK + 16 + hi * 8);
    const short8 kf10 = *(const short8*)(kb + (size_t)(32 + ql) * DQK + hi * 8);
    const short8 kf11 = *(const short8*)(kb + (size_t)(32 + ql) * DQK + 16 + hi * 8);
    f32x16 s0 = __builtin_amdgcn_mfma_f32_32x32x16_bf16(kf00, qf0, zero16(), 0, 0, 0);
    s0 = __builtin_amdgcn_mfma_f32_32x32x16_bf16(kf01, qf1, s0, 0, 0, 0);
    f32x16 s1 = __builtin_amdgcn_mfma_f32_32x32x16_bf16(kf10, qf0, zero16(), 0, 0, 0);
    s1 = __builtin_amdgcn_mfma_f32_32x32x16_bf16(kf11, qf1, s1, 0, 0, 0);

    // ---- online softmax (lane owns q = ql; j split across hi halves) ----
    float mx = s0[0];
    #pragma unroll
    for (int r = 1; r < 16; ++r) mx = fmaxf(mx, s0[r]);
    #pragma unroll
    for (int r = 0; r < 16; ++r) mx = fmaxf(mx, s1[r]);
    mx = fmaxf(mx, __shfl_xor(mx, 32));
    if (!__all(mx <= m + 8.0f)){           // defer-max: rescale only on growth
      const float mnew = fmaxf(m, mx);
      const float al = __expf(m - mnew);
      #pragma unroll
      for (int c = 0; c < 8; ++c) acc[c] = acc[c] * al;
      l *= al; m = mnew;
    }
    float e0[16], e1[16];
    float rs = 0.f;
    #pragma unroll
    for (int r = 0; r < 16; ++r){ e0[r] = __expf(s0[r] - m); rs += e0[r]; }
    #pragma unroll
    for (int r = 0; r < 16; ++r){ e1[r] = __expf(s1[r] - m); rs += e1[r]; }
    rs += __shfl_xor(rs, 32);
    l += rs;

    // ---- pack P -> bf16 B-fragments in-register (shfl across hi halves) ----
    // frag kt (j = kt*16 + hi*8 + e): words [e01,e23,e45,e67]
    u32t pf[4][4];
    #pragma unroll
    for (int js = 0; js < 2; ++js){
      #pragma unroll
      for (int t2 = 0; t2 < 2; ++t2){
        const int base = 8 * t2;
        u32t wA0, wA1, wB0, wB1;
        if (js == 0){
          wA0 = pk2(e0[base+0], e0[base+1]); wA1 = pk2(e0[base+2], e0[base+3]);
          wB0 = pk2(e0[base+4], e0[base+5]); wB1 = pk2(e0[base+6], e0[base+7]);
        } else {
          wA0 = pk2(e1[base+0], e1[base+1]); wA1 = pk2(e1[base+2], e1[base+3]);
          wB0 = pk2(e1[base+4], e1[base+5]); wB1 = pk2(e1[base+6], e1[base+7]);
        }
        const u32t g0 = __shfl_xor(hi ? wA0 : wB0, 32);
        const u32t g1 = __shfl_xor(hi ? wA1 : wB1, 32);
        const int kt = js * 2 + t2;
        pf[kt][0] = hi ? g0 : wA0;
        pf[kt][1] = hi ? g1 : wA1;
        pf[kt][2] = hi ? wB0 : g0;
        pf[kt][3] = hi ? wB1 : g1;
      }
    }

    // ---- PV: O[c][q] += V[c][j] P[j][q] ----
    const u16t* vb = &Vt[cur][0];
    #pragma unroll
    for (int cs = 0; cs < 8; ++cs){
      const int c = cs * 32 + ql;
      #pragma unroll
      for (int kt = 0; kt < 4; ++kt){
        const int slot = (kt * 2 + hi) ^ (c & 7);
        const short8 vf = *(const short8*)(vb + (size_t)c * 64 + slot * 8);
        const short8 pb = __builtin_bit_cast(short8, *(const uint4*)&pf[kt][0]);
        acc[cs] = __builtin_amdgcn_mfma_f32_32x32x16_bf16(vf, pb, acc[cs], 0, 0, 0);
      }
    }
    __syncthreads();   // drains gl_lds (vmcnt) -> next buffers ready
  }

  // ---- epilogue: out = gamma * O/l + x ----
  const float inv = 1.0f / l;
  const float gm = gamma[0];
  const int n = qg + ql;
  #pragma unroll
  for (int cs = 0; cs < 8; ++cs){
    #pragma unroll
    for (int r = 0; r < 16; ++r){
      const int c = cs * 32 + (r & 3) + 8 * (r >> 2) + 4 * hi;
      const size_t idx = ((size_t)b * CCH + c) * NTOK + n;
      out[idx] = gm * (acc[cs][r] * inv) + x[idx];
    }
  }
}

extern "C" void kernel_launch(void* const* d_in, const int* in_sizes, int n_in,
                              void* d_out, int out_size, void* d_ws, size_t ws_size,
                              hipStream_t stream) {
  const float* x     = (const float*)d_in[0];
  const float* Wq    = (const float*)d_in[1];
  const float* bq    = (const float*)d_in[2];
  const float* Wk    = (const float*)d_in[3];
  const float* bk    = (const float*)d_in[4];
  const float* Wv    = (const float*)d_in[5];
  const float* bv    = (const float*)d_in[6];
  const float* gamma = (const float*)d_in[7];
  float* out = (float*)d_out;

  char* ws = (char*)d_ws;
  u16t* xT = (u16t*)(ws);                      // 32 MB
  u16t* Qw = (u16t*)(ws + 33554432);           //  4 MB
  u16t* Kw = (u16t*)(ws + 37748736);           //  4 MB
  u16t* Vw = (u16t*)(ws + 41943040);           // 32 MB  (total 72 MB)

  hipLaunchKernelGGL(k_xpose, dim3(NTOK / 64, CCH / 64, BB), dim3(256), 0, stream,
                     x, xT);
  hipLaunchKernelGGL(k_proj, dim3(NTOK / 64, 5, BB), dim3(256), 0, stream,
                     xT, Wq, bq, Wk, bk, Wv, bv, Qw, Kw, Vw);
  hipLaunchKernelGGL(k_attn, dim3(512), dim3(256), 0, stream,
                     Qw, Kw, Vw, x, gamma, out);
}